// Round 3
// baseline (167195.532 us; speedup 1.0000x reference)
//
#include <hip/hip_runtime.h>

constexpr int NB = 32;    // batch
constexpr int NT = 128;   // time
constexpr int NE = 256;   // embed
constexpr int NH = 256;   // hidden
constexpr int NC = 16;    // classes

typedef _Float16 f16;
typedef f16 f16x2 __attribute__((ext_vector_type(2)));
typedef f16 f16x8 __attribute__((ext_vector_type(8)));

__device__ __forceinline__ float sigmoidf_(float x) {
    return 1.f / (1.f + __expf(-x));
}
__device__ __forceinline__ float tanhf_(float x) {
    x = fminf(fmaxf(x, -15.f), 15.f);
    float e = __expf(-2.f * x);
    return (1.f - e) / (1.f + e);
}
__device__ __forceinline__ float dot4_(float4 a, float4 b) {
    return a.x * b.x + a.y * b.y + a.z * b.z + a.w * b.w;
}
#if __has_builtin(__builtin_amdgcn_fdot2)
__device__ __forceinline__ float fdot2_(f16x2 a, f16x2 b, float c) {
    return __builtin_amdgcn_fdot2(a, b, c, false);
}
#else
__device__ __forceinline__ float fdot2_(f16x2 a, f16x2 b, float c) {
    return (float)a[0] * (float)b[0] + (float)a[1] * (float)b[1] + c;
}
#endif
#define PAIR(v, k) __builtin_shufflevector((v), (v), (k), (k) + 1)

// ---------------- Prologue 1: xp[t][b][j] = x[b][t][:] . W_in[j][:] + b_in[j]
__global__ __launch_bounds__(256) void k_lin_in(
    const float* __restrict__ x, const float* __restrict__ W_in,
    const float* __restrict__ b_in, float* __restrict__ xp) {
    const int tb = blockIdx.x;           // t*NB + b
    const int t = tb >> 5, b = tb & 31;
    const int tid = threadIdx.x;
    __shared__ __align__(16) float xl[NE];
    xl[tid] = x[(b * NT + t) * NE + tid];
    __syncthreads();
    const float* __restrict__ wr = W_in + tid * NE;
    float acc = b_in[tid];
#pragma unroll 8
    for (int k = 0; k < NE; k += 4)
        acc += dot4_(*(const float4*)(wr + k), *(const float4*)(xl + k));
    xp[tb * NH + tid] = acc;
}

// ---------------- Prologue 2: xw = xp.Wih^T + bih ; uax = xp.Ua^T + ub
__global__ __launch_bounds__(256) void k_proj(
    const float* __restrict__ xp, const float* __restrict__ Wih,
    const float* __restrict__ bih, const float* __restrict__ Ua,
    const float* __restrict__ ub, float* __restrict__ xw,
    float* __restrict__ uax) {
    const int tb = blockIdx.x;
    const int tid = threadIdx.x;
    __shared__ __align__(16) float xl[NH];
    xl[tid] = xp[tb * NH + tid];
    __syncthreads();
    const float* __restrict__ wr = Wih + tid * NH;
    const float* __restrict__ wz = Wih + (NH + tid) * NH;
    const float* __restrict__ wn = Wih + (2 * NH + tid) * NH;
    const float* __restrict__ wu = Ua + tid * NH;
    float ar = bih[tid], az = bih[NH + tid], an = bih[2 * NH + tid], au = ub[tid];
#pragma unroll 4
    for (int k = 0; k < NH; k += 4) {
        float4 xv = *(const float4*)(xl + k);
        ar += dot4_(*(const float4*)(wr + k), xv);
        az += dot4_(*(const float4*)(wz + k), xv);
        an += dot4_(*(const float4*)(wn + k), xv);
        au += dot4_(*(const float4*)(wu + k), xv);
    }
    float* xwp = xw + tb * (3 * NH);
    xwp[tid] = ar;
    xwp[NH + tid] = az;
    xwp[2 * NH + tid] = an;
    uax[tb * NH + tid] = au;
}

// ---------------- Main: 1 WG / batch element. Whh fp16 in VGPRs, Wa fp16 in LDS.
// __launch_bounds__(512, 1): 2 waves/SIMD -> 256-VGPR budget. (512,2) capped
// VGPRs at 128 and spilled the 192 weight registers to scratch (round 2 bug).
__global__ __launch_bounds__(512, 1) void k_main(
    const float* __restrict__ Whh, const float* __restrict__ bhh,
    const float* __restrict__ Wa, const float* __restrict__ ba,
    const float* __restrict__ va_w, const float* __restrict__ Wo,
    const float* __restrict__ bo, const float* __restrict__ xp,
    const float* __restrict__ xw, const float* __restrict__ uax,
    f16* __restrict__ outsW, float* __restrict__ out) {
    const int b = blockIdx.x;
    const int tid = threadIdx.x;
    const int lane = tid & 63, wid = tid >> 6;
    const int j = tid >> 1, c = tid & 1;   // output row j, k-chunk c (128 wide)

    // Wa rows padded to 132 pairs (528 B) so consecutive j shift banks by 4.
    __shared__ __align__(16) f16x2 WaH[NH * 132];          // 132 KB
    __shared__ __align__(16) f16 hbuf[2][NH];
    __shared__ float hlast[NH];
    __shared__ float scores[NT], wsm[NT];
    __shared__ float redA[8][4];
    __shared__ float redo[4 * NC];

    // ---- persist Whh (fp16) in registers: 3 gates x 64 f16x2 = 192 VGPRs
    f16x2 wr[64], wz[64], wn[64];
    {
        const float2* pr = (const float2*)(Whh + (0 * NH + j) * NH + c * 128);
        const float2* pz = (const float2*)(Whh + (1 * NH + j) * NH + c * 128);
        const float2* pn = (const float2*)(Whh + (2 * NH + j) * NH + c * 128);
#pragma unroll
        for (int m = 0; m < 64; ++m) {
            float2 a = pr[m]; wr[m] = f16x2{(f16)a.x, (f16)a.y};
            float2 d = pz[m]; wz[m] = f16x2{(f16)d.x, (f16)d.y};
            float2 e = pn[m]; wn[m] = f16x2{(f16)e.x, (f16)e.y};
        }
    }
    // ---- stage Wa into LDS as fp16 pairs
    for (int e = tid; e < NH * 128; e += 512) {
        const int jj = e >> 7, kp = e & 127;
        const float2 v = *(const float2*)(Wa + jj * NH + kp * 2);
        WaH[jj * 132 + kp] = f16x2{(f16)v.x, (f16)v.y};
    }
    if (tid < NH) hbuf[0][tid] = (f16)0.f;

    const float bhr = bhh[j], bhz = bhh[NH + j], bhn = bhh[2 * NH + j];
    const float ba_j = ba[j], va_j = va_w[j];
    f16* __restrict__ ob = outsW + (size_t)b * NT * NH;
    const float* __restrict__ xpB = xp + b * NH;
    const float* __restrict__ uaxB = uax + b * NH;
    float hprev = 0.f;
    int cur = 0;
    __syncthreads();

    for (int i = 0; i < NT; ++i) {
        // ======== GRU chain over prefix t = 0..i (carried hidden) ========
        for (int t = 0; t <= i; ++t) {
            const float* __restrict__ xwp = xw + (size_t)(t * NB + b) * (3 * NH);
            const float xr = xwp[j], xz = xwp[NH + j], xn = xwp[2 * NH + j];
            const f16* hc = hbuf[cur] + c * 128;
            float ar = 0.f, az = 0.f, an = 0.f;
#pragma unroll
            for (int q = 0; q < 16; ++q) {
                const f16x8 hv = *(const f16x8*)(hc + q * 8);
                const f16x2 h0 = PAIR(hv, 0), h1 = PAIR(hv, 2),
                            h2 = PAIR(hv, 4), h3 = PAIR(hv, 6);
                ar = fdot2_(wr[q * 4 + 0], h0, ar);
                ar = fdot2_(wr[q * 4 + 1], h1, ar);
                ar = fdot2_(wr[q * 4 + 2], h2, ar);
                ar = fdot2_(wr[q * 4 + 3], h3, ar);
                az = fdot2_(wz[q * 4 + 0], h0, az);
                az = fdot2_(wz[q * 4 + 1], h1, az);
                az = fdot2_(wz[q * 4 + 2], h2, az);
                az = fdot2_(wz[q * 4 + 3], h3, az);
                an = fdot2_(wn[q * 4 + 0], h0, an);
                an = fdot2_(wn[q * 4 + 1], h1, an);
                an = fdot2_(wn[q * 4 + 2], h2, an);
                an = fdot2_(wn[q * 4 + 3], h3, an);
            }
            ar += __shfl_xor(ar, 1);
            az += __shfl_xor(az, 1);
            an += __shfl_xor(an, 1);
            const float r = sigmoidf_(xr + ar + bhr);
            const float z = sigmoidf_(xz + az + bhz);
            const float n = tanhf_(xn + r * (an + bhn));
            const float hnew = (1.f - z) * n + z * hprev;
            hprev = hnew;
            if (c) {
                hbuf[cur ^ 1][j] = (f16)hnew;
            } else {
                ob[t * NH + j] = (f16)hnew;
                if (t == i) hlast[j] = hnew;
            }
            cur ^= 1;
            __syncthreads();
        }
        __threadfence_block();

        // ======== attention scores for t = 0..i (4 rows per pass) ========
        for (int t0 = 0; t0 <= i; t0 += 4) {
            const f16x2* wrow = WaH + j * 132 + c * 64;
            const f16x8* op[4];
#pragma unroll
            for (int tt = 0; tt < 4; ++tt)
                op[tt] = (const f16x8*)(ob + (t0 + tt) * NH + c * 128);
            float acc[4] = {0.f, 0.f, 0.f, 0.f};
#pragma unroll
            for (int q = 0; q < 16; ++q) {
                const f16x8 wv = *(const f16x8*)(wrow + q * 4);
                const f16x2 w0 = PAIR(wv, 0), w1 = PAIR(wv, 2),
                            w2 = PAIR(wv, 4), w3 = PAIR(wv, 6);
#pragma unroll
                for (int tt = 0; tt < 4; ++tt) {
                    const f16x8 v = op[tt][q];
                    acc[tt] = fdot2_(w0, PAIR(v, 0), acc[tt]);
                    acc[tt] = fdot2_(w1, PAIR(v, 2), acc[tt]);
                    acc[tt] = fdot2_(w2, PAIR(v, 4), acc[tt]);
                    acc[tt] = fdot2_(w3, PAIR(v, 6), acc[tt]);
                }
            }
#pragma unroll
            for (int tt = 0; tt < 4; ++tt) {
                float s = acc[tt];
                s += __shfl_xor(s, 1);
                const float sv = s + ba_j + uaxB[(size_t)(t0 + tt) * NB * NH + j];
                float contrib = (c == 0) ? va_j * tanhf_(sv) : 0.f;
#pragma unroll
                for (int off = 32; off; off >>= 1) contrib += __shfl_xor(contrib, off);
                if (lane == 0) redA[wid][tt] = contrib;
            }
            __syncthreads();
            if (tid < 4) {
                float s = 0.f;
#pragma unroll
                for (int w = 0; w < 8; ++w) s += redA[w][tid];
                scores[t0 + tid] = s;
            }
            __syncthreads();
        }

        // ======== softmax over t = 0..i (va_b cancels) ========
        if (tid < 64) {
            float s1 = (tid <= i) ? scores[tid] : -1e30f;
            float s2 = (64 + tid <= i) ? scores[64 + tid] : -1e30f;
            float m = fmaxf(s1, s2);
#pragma unroll
            for (int off = 32; off; off >>= 1) m = fmaxf(m, __shfl_xor(m, off));
            float e1 = (tid <= i) ? __expf(s1 - m) : 0.f;
            float e2 = (64 + tid <= i) ? __expf(s2 - m) : 0.f;
            float ssum = e1 + e2;
#pragma unroll
            for (int off = 32; off; off >>= 1) ssum += __shfl_xor(ssum, off);
            const float inv = 1.f / ssum;
            wsm[tid] = e1 * inv;
            wsm[64 + tid] = e2 * inv;
        }
        __syncthreads();

        // ======== context + output head (waves 0-3) ========
        if (tid < NH) {
            float ctx = 0.f;
            for (int t = 0; t <= i; ++t) ctx += wsm[t] * xpB[(size_t)t * NB * NH + tid];
            const float hl = hlast[tid];
#pragma unroll
            for (int cc = 0; cc < NC; ++cc) {
                float p = Wo[cc * (2 * NH) + tid] * hl + Wo[cc * (2 * NH) + NH + tid] * ctx;
#pragma unroll
                for (int off = 32; off; off >>= 1) p += __shfl_xor(p, off);
                if (lane == 0) redo[wid * NC + cc] = p;
            }
        }
        __syncthreads();
        if (tid < NC) {
            const float lg = redo[tid] + redo[NC + tid] + redo[2 * NC + tid] +
                             redo[3 * NC + tid] + bo[tid];
            out[((size_t)b * NT + i) * NC + tid] = sigmoidf_(lg);
        }
        __syncthreads();
    }
}

extern "C" void kernel_launch(void* const* d_in, const int* in_sizes, int n_in,
                              void* d_out, int out_size, void* d_ws, size_t ws_size,
                              hipStream_t stream) {
    (void)in_sizes; (void)n_in; (void)out_size; (void)ws_size;
    const float* x    = (const float*)d_in[0];
    const float* W_in = (const float*)d_in[1];
    const float* b_in = (const float*)d_in[2];
    const float* Wih  = (const float*)d_in[3];
    const float* bih  = (const float*)d_in[4];
    const float* Whh  = (const float*)d_in[5];
    const float* bhh  = (const float*)d_in[6];
    const float* Wa   = (const float*)d_in[7];
    const float* ba   = (const float*)d_in[8];
    const float* Ua   = (const float*)d_in[9];
    const float* ub   = (const float*)d_in[10];
    const float* va_w = (const float*)d_in[11];
    // d_in[12] = va_b: cancels in softmax
    const float* Wo   = (const float*)d_in[13];
    const float* bo   = (const float*)d_in[14];
    float* out = (float*)d_out;

    float* ws   = (float*)d_ws;
    float* xp   = ws;                                   // NT*NB*NH floats
    float* xw   = xp  + (size_t)NT * NB * NH;           // NT*NB*3NH floats
    float* uax  = xw  + (size_t)NT * NB * 3 * NH;       // NT*NB*NH floats
    f16*   outsW = (f16*)(uax + (size_t)NT * NB * NH);  // NB*NT*NH halves

    hipLaunchKernelGGL(k_lin_in, dim3(NT * NB), dim3(256), 0, stream, x, W_in, b_in, xp);
    hipLaunchKernelGGL(k_proj,   dim3(NT * NB), dim3(256), 0, stream, xp, Wih, bih, Ua, ub, xw, uax);
    hipLaunchKernelGGL(k_main,   dim3(NB),      dim3(512), 0, stream,
                       Whh, bhh, Wa, ba, va_w, Wo, bo, xp, xw, uax, outsW, out);
}

// Round 4
// 18489.569 us; speedup vs baseline: 9.0427x; 9.0427x over previous
//
#include <hip/hip_runtime.h>

constexpr int NB = 32;    // batch
constexpr int NT = 128;   // time
constexpr int NE = 256;   // embed
constexpr int NH = 256;   // hidden
constexpr int NC = 16;    // classes

typedef _Float16 f16;
typedef f16 f16x2 __attribute__((ext_vector_type(2)));
typedef f16 f16x8 __attribute__((ext_vector_type(8)));

__device__ __forceinline__ float sigmoidf_(float x) {
    return 1.f / (1.f + __expf(-x));
}
__device__ __forceinline__ float tanhf_(float x) {
    x = fminf(fmaxf(x, -15.f), 15.f);
    float e = __expf(-2.f * x);
    return (1.f - e) / (1.f + e);
}
__device__ __forceinline__ float dot4_(float4 a, float4 b) {
    return a.x * b.x + a.y * b.y + a.z * b.z + a.w * b.w;
}
#if __has_builtin(__builtin_amdgcn_fdot2)
__device__ __forceinline__ float fdot2_(f16x2 a, f16x2 b, float c) {
    return __builtin_amdgcn_fdot2(a, b, c, false);
}
#else
__device__ __forceinline__ float fdot2_(f16x2 a, f16x2 b, float c) {
    return (float)a[0] * (float)b[0] + (float)a[1] * (float)b[1] + c;
}
#endif
#define PAIR(v, k) __builtin_shufflevector((v), (v), (k), (k) + 1)

// ---------------- Prologue 1: xp[t][b][j] = x[b][t][:] . W_in[j][:] + b_in[j]
__global__ __launch_bounds__(256) void k_lin_in(
    const float* __restrict__ x, const float* __restrict__ W_in,
    const float* __restrict__ b_in, float* __restrict__ xp) {
    const int tb = blockIdx.x;           // t*NB + b
    const int t = tb >> 5, b = tb & 31;
    const int tid = threadIdx.x;
    __shared__ __align__(16) float xl[NE];
    xl[tid] = x[(b * NT + t) * NE + tid];
    __syncthreads();
    const float* __restrict__ wr = W_in + tid * NE;
    float acc = b_in[tid];
#pragma unroll 8
    for (int k = 0; k < NE; k += 4)
        acc += dot4_(*(const float4*)(wr + k), *(const float4*)(xl + k));
    xp[tb * NH + tid] = acc;
}

// ---------------- Prologue 2: xw = xp.Wih^T + bih ; uax = xp.Ua^T + ub
__global__ __launch_bounds__(256) void k_proj(
    const float* __restrict__ xp, const float* __restrict__ Wih,
    const float* __restrict__ bih, const float* __restrict__ Ua,
    const float* __restrict__ ub, float* __restrict__ xw,
    float* __restrict__ uax) {
    const int tb = blockIdx.x;
    const int tid = threadIdx.x;
    __shared__ __align__(16) float xl[NH];
    xl[tid] = xp[tb * NH + tid];
    __syncthreads();
    const float* __restrict__ wr = Wih + tid * NH;
    const float* __restrict__ wz = Wih + (NH + tid) * NH;
    const float* __restrict__ wn = Wih + (2 * NH + tid) * NH;
    const float* __restrict__ wu = Ua + tid * NH;
    float ar = bih[tid], az = bih[NH + tid], an = bih[2 * NH + tid], au = ub[tid];
#pragma unroll 4
    for (int k = 0; k < NH; k += 4) {
        float4 xv = *(const float4*)(xl + k);
        ar += dot4_(*(const float4*)(wr + k), xv);
        az += dot4_(*(const float4*)(wz + k), xv);
        an += dot4_(*(const float4*)(wn + k), xv);
        au += dot4_(*(const float4*)(wu + k), xv);
    }
    float* xwp = xw + tb * (3 * NH);
    xwp[tid] = ar;
    xwp[NH + tid] = az;
    xwp[2 * NH + tid] = an;
    uax[tb * NH + tid] = au;
}

// ---------------- Pack Whh/Wa to f16x8 [kc][row] so k_attn's loads coalesce.
// Wpk[kc*768 + row] = Whh[row][kc*8 .. kc*8+7];  Wak[kc*256 + row] likewise.
__global__ __launch_bounds__(256) void k_pack(
    const float* __restrict__ Whh, const float* __restrict__ Wa,
    f16x8* __restrict__ Wpk, f16x8* __restrict__ Wak) {
    const int id = blockIdx.x * 256 + threadIdx.x;
    if (id < 32 * 768) {
        const int kc = id / 768, row = id % 768;
        const float* src = Whh + row * NH + kc * 8;
        f16x8 v;
#pragma unroll
        for (int m = 0; m < 8; ++m) v[m] = (f16)src[m];
        Wpk[id] = v;
    } else {
        const int id2 = id - 32 * 768;   // < 8192
        const int kc = id2 >> 8, row = id2 & 255;
        const float* src = Wa + row * NH + kc * 8;
        f16x8 v;
#pragma unroll
        for (int m = 0; m < 8; ++m) v[m] = (f16)src[m];
        Wak[id2] = v;
    }
}

// ---------------- Phase 1: sequential carried-hidden chain. 1 WG / batch.
// 1024 threads: j = tid>>2 (row), c = tid&3 (64-wide k-chunk). Weights = 96 VGPRs.
__global__ __launch_bounds__(1024) void k_chain(
    const float* __restrict__ Whh, const float* __restrict__ bhh,
    const float* __restrict__ xw, float* __restrict__ Hc) {
    const int b = blockIdx.x;
    const int tid = threadIdx.x;
    const int j = tid >> 2, c = tid & 3;
    __shared__ __align__(16) f16 hb[2][NH];

    f16x2 wr[32], wz[32], wn[32];
    {
        const float2* pr = (const float2*)(Whh + (size_t)(0 * NH + j) * NH + c * 64);
        const float2* pz = (const float2*)(Whh + (size_t)(1 * NH + j) * NH + c * 64);
        const float2* pn = (const float2*)(Whh + (size_t)(2 * NH + j) * NH + c * 64);
#pragma unroll
        for (int m = 0; m < 32; ++m) {
            float2 a = pr[m]; wr[m] = f16x2{(f16)a.x, (f16)a.y};
            float2 d = pz[m]; wz[m] = f16x2{(f16)d.x, (f16)d.y};
            float2 e = pn[m]; wn[m] = f16x2{(f16)e.x, (f16)e.y};
        }
    }
    const float bhr = bhh[j], bhz = bhh[NH + j], bhn = bhh[2 * NH + j];
    if (tid < NH) hb[0][tid] = (f16)0.f;
    float hprev = 0.f;
    int cur = 0;
    __syncthreads();

#pragma unroll 1
    for (int i = 0; i < NT; ++i) {
#pragma unroll 1
        for (int t = 0; t <= i; ++t) {
            const float* __restrict__ xwp = xw + (size_t)(t * NB + b) * (3 * NH);
            const float xr = xwp[j], xz = xwp[NH + j], xn = xwp[2 * NH + j];
            const f16* hc = hb[cur] + c * 64;
            float ar = 0.f, az = 0.f, an = 0.f;
#pragma unroll
            for (int s = 0; s < 8; ++s) {
                const f16x8 hv = *(const f16x8*)(hc + s * 8);
                const f16x2 h0 = PAIR(hv, 0), h1 = PAIR(hv, 2),
                            h2 = PAIR(hv, 4), h3 = PAIR(hv, 6);
                ar = fdot2_(wr[s * 4 + 0], h0, ar);
                ar = fdot2_(wr[s * 4 + 1], h1, ar);
                ar = fdot2_(wr[s * 4 + 2], h2, ar);
                ar = fdot2_(wr[s * 4 + 3], h3, ar);
                az = fdot2_(wz[s * 4 + 0], h0, az);
                az = fdot2_(wz[s * 4 + 1], h1, az);
                az = fdot2_(wz[s * 4 + 2], h2, az);
                az = fdot2_(wz[s * 4 + 3], h3, az);
                an = fdot2_(wn[s * 4 + 0], h0, an);
                an = fdot2_(wn[s * 4 + 1], h1, an);
                an = fdot2_(wn[s * 4 + 2], h2, an);
                an = fdot2_(wn[s * 4 + 3], h3, an);
            }
            ar += __shfl_xor(ar, 1); ar += __shfl_xor(ar, 2);
            az += __shfl_xor(az, 1); az += __shfl_xor(az, 2);
            an += __shfl_xor(an, 1); an += __shfl_xor(an, 2);
            const float r = sigmoidf_(xr + ar + bhr);
            const float z = sigmoidf_(xz + az + bhz);
            const float n = tanhf_(xn + r * (an + bhn));
            const float hnew = (1.f - z) * n + z * hprev;
            hprev = hnew;
            if (c == 0) {
                hb[cur ^ 1][j] = (f16)hnew;
                if (t == i) Hc[((size_t)i * NB + b) * NH + j] = hnew;
            }
            cur ^= 1;
            __syncthreads();
        }
    }
}

// ---------------- Phase 2: lockstep re-run of all prefix chains + fused attention.
// Grid: 32 b x 8 blocks; each WG owns 16 chains i = bk + 8u (u=0..15), 256 threads.
// Thread tid = column j; computes gate rows {tid, 256+tid, 512+tid} per chain.
__global__ __launch_bounds__(256) void k_attn(
    const float* __restrict__ Hc, const float* __restrict__ xw,
    const float* __restrict__ uax, const float* __restrict__ xp,
    const f16x8* __restrict__ Wpk, const f16x8* __restrict__ Wak,
    const float* __restrict__ bhh, const float* __restrict__ ba,
    const float* __restrict__ va_w, const float* __restrict__ Wo,
    const float* __restrict__ bo, float* __restrict__ out) {
    const int b  = blockIdx.x >> 3;
    const int bk = blockIdx.x & 7;
    const int tid = threadIdx.x;
    const int lane = tid & 63, wid = tid >> 6;

    __shared__ __align__(16) float S[16][NH];
    __shared__ __align__(16) f16 Sh[16][NH];
    __shared__ float red1[4][16];
    __shared__ float mL[16], lL[16], aL[16], eL[16];
    __shared__ float redH[4][256];

    const float bhr = bhh[tid], bhz = bhh[NH + tid], bhn = bhh[2 * NH + tid];
    const float ba_j = ba[tid], va_j = va_w[tid];
    float ctx[16];
#pragma unroll
    for (int u = 0; u < 16; ++u) {
        const int ic = bk + 8 * u;
        const float hv = (ic == 0) ? 0.f : Hc[((size_t)(ic - 1) * NB + b) * NH + tid];
        S[u][tid] = hv;
        Sh[u][tid] = (f16)hv;
        ctx[u] = 0.f;
    }
    if (tid < 16) { mL[tid] = -1e30f; lL[tid] = 0.f; }
    __syncthreads();

    const int imax = bk + 8 * 15;
#pragma unroll 1
    for (int t = 0; t <= imax; ++t) {
        const size_t base = (size_t)(t * NB + b);
        const float xr = xw[base * 3 * NH + tid];
        const float xz = xw[base * 3 * NH + NH + tid];
        const float xn = xw[base * 3 * NH + 2 * NH + tid];
        const float ux = uax[base * NH + tid];
        const float xpt = xp[base * NH + tid];

        // ---- GRU matvec for all active chains (i >= t)
        float ar[16], az[16], an[16];
#pragma unroll
        for (int u = 0; u < 16; ++u) { ar[u] = 0.f; az[u] = 0.f; an[u] = 0.f; }
#pragma unroll 1
        for (int kc = 0; kc < 32; ++kc) {
            const f16x8 wR = Wpk[kc * 768 + tid];
            const f16x8 wZ = Wpk[kc * 768 + 256 + tid];
            const f16x8 wN = Wpk[kc * 768 + 512 + tid];
#pragma unroll
            for (int u = 0; u < 16; ++u) {
                if (bk + 8 * u < t) continue;      // frozen chain: skip (uniform branch)
                const f16x8 hv = *(const f16x8*)&Sh[u][kc * 8];
                const f16x2 h0 = PAIR(hv, 0), h1 = PAIR(hv, 2),
                            h2 = PAIR(hv, 4), h3 = PAIR(hv, 6);
                ar[u] = fdot2_(PAIR(wR, 0), h0, ar[u]);
                ar[u] = fdot2_(PAIR(wR, 2), h1, ar[u]);
                ar[u] = fdot2_(PAIR(wR, 4), h2, ar[u]);
                ar[u] = fdot2_(PAIR(wR, 6), h3, ar[u]);
                az[u] = fdot2_(PAIR(wZ, 0), h0, az[u]);
                az[u] = fdot2_(PAIR(wZ, 2), h1, az[u]);
                az[u] = fdot2_(PAIR(wZ, 4), h2, az[u]);
                az[u] = fdot2_(PAIR(wZ, 6), h3, az[u]);
                an[u] = fdot2_(PAIR(wN, 0), h0, an[u]);
                an[u] = fdot2_(PAIR(wN, 2), h1, an[u]);
                an[u] = fdot2_(PAIR(wN, 4), h2, an[u]);
                an[u] = fdot2_(PAIR(wN, 6), h3, an[u]);
            }
        }
        float hn[16];
#pragma unroll
        for (int u = 0; u < 16; ++u) {
            if (bk + 8 * u < t) continue;
            const float r = sigmoidf_(xr + ar[u] + bhr);
            const float z = sigmoidf_(xz + az[u] + bhz);
            const float n = tanhf_(xn + r * (an[u] + bhn));
            hn[u] = (1.f - z) * n + z * S[u][tid];
        }
        __syncthreads();                      // all Sh reads of this step done
#pragma unroll
        for (int u = 0; u < 16; ++u) {
            if (bk + 8 * u < t) continue;
            S[u][tid] = hn[u];
            Sh[u][tid] = (f16)hn[u];
        }
        __syncthreads();                      // Sh now holds outs[t]

        // ---- attention scores for active chains
        float sc[16];
#pragma unroll
        for (int u = 0; u < 16; ++u) sc[u] = 0.f;
#pragma unroll 1
        for (int kc = 0; kc < 32; ++kc) {
            const f16x8 wA = Wak[kc * 256 + tid];
#pragma unroll
            for (int u = 0; u < 16; ++u) {
                if (bk + 8 * u < t) continue;
                const f16x8 hv = *(const f16x8*)&Sh[u][kc * 8];
                sc[u] = fdot2_(PAIR(wA, 0), PAIR(hv, 0), sc[u]);
                sc[u] = fdot2_(PAIR(wA, 2), PAIR(hv, 2), sc[u]);
                sc[u] = fdot2_(PAIR(wA, 4), PAIR(hv, 4), sc[u]);
                sc[u] = fdot2_(PAIR(wA, 6), PAIR(hv, 6), sc[u]);
            }
        }
#pragma unroll
        for (int u = 0; u < 16; ++u) {
            if (bk + 8 * u < t) continue;
            float p = va_j * tanhf_(sc[u] + ba_j + ux);
#pragma unroll
            for (int off = 32; off; off >>= 1) p += __shfl_xor(p, off);
            if (lane == 0) red1[wid][u] = p;
        }
        __syncthreads();
        if (tid < 16 && bk + 8 * tid >= t) {   // online softmax state per chain
            const float s  = red1[0][tid] + red1[1][tid] + red1[2][tid] + red1[3][tid];
            const float mo = mL[tid];
            const float mn = fmaxf(mo, s);
            const float e  = __expf(s - mn);
            const float al = __expf(mo - mn);
            lL[tid] = lL[tid] * al + e;
            mL[tid] = mn; aL[tid] = al; eL[tid] = e;
        }
        __syncthreads();
#pragma unroll
        for (int u = 0; u < 16; ++u) {
            if (bk + 8 * u < t) continue;
            ctx[u] = ctx[u] * aL[u] + eL[u] * xpt;
        }
    }

    // ---- output head per chain: logits = [h_last, context] @ Wo^T + bo
#pragma unroll 1
    for (int u = 0; u < 16; ++u) {
        const float hl = S[u][tid];           // final state == h_last(i)
        const float cx = ctx[u] / lL[u];
#pragma unroll
        for (int cls = 0; cls < NC; ++cls) {
            float p = Wo[cls * (2 * NH) + tid] * hl + Wo[cls * (2 * NH) + NH + tid] * cx;
#pragma unroll
            for (int off = 32; off; off >>= 1) p += __shfl_xor(p, off);
            if (lane == 0) redH[wid][u * 16 + cls] = p;
        }
    }
    __syncthreads();
    {
        const int u = tid >> 4, cls = tid & 15;
        const int ic = bk + 8 * u;
        const float lg = redH[0][tid] + redH[1][tid] + redH[2][tid] + redH[3][tid] + bo[cls];
        out[((size_t)b * NT + ic) * NC + cls] = sigmoidf_(lg);
    }
}

extern "C" void kernel_launch(void* const* d_in, const int* in_sizes, int n_in,
                              void* d_out, int out_size, void* d_ws, size_t ws_size,
                              hipStream_t stream) {
    (void)in_sizes; (void)n_in; (void)out_size; (void)ws_size;
    const float* x    = (const float*)d_in[0];
    const float* W_in = (const float*)d_in[1];
    const float* b_in = (const float*)d_in[2];
    const float* Wih  = (const float*)d_in[3];
    const float* bih  = (const float*)d_in[4];
    const float* Whh  = (const float*)d_in[5];
    const float* bhh  = (const float*)d_in[6];
    const float* Wa   = (const float*)d_in[7];
    const float* ba   = (const float*)d_in[8];
    const float* Ua   = (const float*)d_in[9];
    const float* ub   = (const float*)d_in[10];
    const float* va_w = (const float*)d_in[11];
    // d_in[12] = va_b: cancels in softmax
    const float* Wo   = (const float*)d_in[13];
    const float* bo   = (const float*)d_in[14];
    float* out = (float*)d_out;

    float* ws  = (float*)d_ws;
    float* xp  = ws;                                    // NT*NB*NH        (4 MB)
    float* xw  = xp  + (size_t)NT * NB * NH;            // NT*NB*3NH       (12.6 MB)
    float* uax = xw  + (size_t)NT * NB * 3 * NH;        // NT*NB*NH        (4 MB)
    float* Hc  = uax + (size_t)NT * NB * NH;            // NT*NB*NH        (4 MB)
    f16x8* Wpk = (f16x8*)(Hc + (size_t)NT * NB * NH);   // 32*768 f16x8    (384 KB)
    f16x8* Wak = Wpk + 32 * 768;                        // 32*256 f16x8    (128 KB)

    hipLaunchKernelGGL(k_lin_in, dim3(NT * NB), dim3(256), 0, stream, x, W_in, b_in, xp);
    hipLaunchKernelGGL(k_proj,   dim3(NT * NB), dim3(256), 0, stream, xp, Wih, bih, Ua, ub, xw, uax);
    hipLaunchKernelGGL(k_pack,   dim3(128),     dim3(256), 0, stream, Whh, Wa, Wpk, Wak);
    hipLaunchKernelGGL(k_chain,  dim3(NB),      dim3(1024), 0, stream, Whh, bhh, xw, Hc);
    hipLaunchKernelGGL(k_attn,   dim3(NB * 8),  dim3(256), 0, stream,
                       Hc, xw, uax, xp, Wpk, Wak, bhh, ba, va_w, Wo, bo, out);
}

// Round 5
// 16094.334 us; speedup vs baseline: 10.3885x; 1.1488x over previous
//
#include <hip/hip_runtime.h>

constexpr int NB = 32;    // batch
constexpr int NT = 128;   // time
constexpr int NE = 256;   // embed
constexpr int NH = 256;   // hidden
constexpr int NC = 16;    // classes

typedef _Float16 f16;
typedef f16 f16x2 __attribute__((ext_vector_type(2)));
typedef f16 f16x8 __attribute__((ext_vector_type(8)));

__device__ __forceinline__ float sigmoidf_(float x) {
    return 1.f / (1.f + __expf(-x));
}
__device__ __forceinline__ float tanhf_(float x) {
    x = fminf(fmaxf(x, -15.f), 15.f);
    float e = __expf(-2.f * x);
    return (1.f - e) / (1.f + e);
}
__device__ __forceinline__ float dot4_(float4 a, float4 b) {
    return a.x * b.x + a.y * b.y + a.z * b.z + a.w * b.w;
}
#if __has_builtin(__builtin_amdgcn_fdot2)
__device__ __forceinline__ float fdot2_(f16x2 a, f16x2 b, float c) {
    return __builtin_amdgcn_fdot2(a, b, c, false);
}
#else
__device__ __forceinline__ float fdot2_(f16x2 a, f16x2 b, float c) {
    return (float)a[0] * (float)b[0] + (float)a[1] * (float)b[1] + c;
}
#endif
#define PAIR(v, k) __builtin_shufflevector((v), (v), (k), (k) + 1)

// ---------------- Prologue 1: xp[t][b][j] = x[b][t][:] . W_in[j][:] + b_in[j]
__global__ __launch_bounds__(256) void k_lin_in(
    const float* __restrict__ x, const float* __restrict__ W_in,
    const float* __restrict__ b_in, float* __restrict__ xp) {
    const int tb = blockIdx.x;           // t*NB + b
    const int t = tb >> 5, b = tb & 31;
    const int tid = threadIdx.x;
    __shared__ __align__(16) float xl[NE];
    xl[tid] = x[(b * NT + t) * NE + tid];
    __syncthreads();
    const float* __restrict__ wr = W_in + tid * NE;
    float acc = b_in[tid];
#pragma unroll 8
    for (int k = 0; k < NE; k += 4)
        acc += dot4_(*(const float4*)(wr + k), *(const float4*)(xl + k));
    xp[tb * NH + tid] = acc;
}

// ---------------- Prologue 2: xw = xp.Wih^T + bih ; uax = xp.Ua^T + ub
__global__ __launch_bounds__(256) void k_proj(
    const float* __restrict__ xp, const float* __restrict__ Wih,
    const float* __restrict__ bih, const float* __restrict__ Ua,
    const float* __restrict__ ub, float* __restrict__ xw,
    float* __restrict__ uax) {
    const int tb = blockIdx.x;
    const int tid = threadIdx.x;
    __shared__ __align__(16) float xl[NH];
    xl[tid] = xp[tb * NH + tid];
    __syncthreads();
    const float* __restrict__ wr = Wih + tid * NH;
    const float* __restrict__ wz = Wih + (NH + tid) * NH;
    const float* __restrict__ wn = Wih + (2 * NH + tid) * NH;
    const float* __restrict__ wu = Ua + tid * NH;
    float ar = bih[tid], az = bih[NH + tid], an = bih[2 * NH + tid], au = ub[tid];
#pragma unroll 4
    for (int k = 0; k < NH; k += 4) {
        float4 xv = *(const float4*)(xl + k);
        ar += dot4_(*(const float4*)(wr + k), xv);
        az += dot4_(*(const float4*)(wz + k), xv);
        an += dot4_(*(const float4*)(wn + k), xv);
        au += dot4_(*(const float4*)(wu + k), xv);
    }
    float* xwp = xw + tb * (3 * NH);
    xwp[tid] = ar;
    xwp[NH + tid] = az;
    xwp[2 * NH + tid] = an;
    uax[tb * NH + tid] = au;
}

// ---------------- Pack Whh/Wa to f16x8 [kc][row] so k_attn's loads coalesce.
__global__ __launch_bounds__(256) void k_pack(
    const float* __restrict__ Whh, const float* __restrict__ Wa,
    f16x8* __restrict__ Wpk, f16x8* __restrict__ Wak) {
    const int id = blockIdx.x * 256 + threadIdx.x;
    if (id < 32 * 768) {
        const int kc = id / 768, row = id % 768;
        const float* src = Whh + row * NH + kc * 8;
        f16x8 v;
#pragma unroll
        for (int m = 0; m < 8; ++m) v[m] = (f16)src[m];
        Wpk[id] = v;
    } else {
        const int id2 = id - 32 * 768;   // < 8192
        const int kc = id2 >> 8, row = id2 & 255;
        const float* src = Wa + row * NH + kc * 8;
        f16x8 v;
#pragma unroll
        for (int m = 0; m < 8; ++m) v[m] = (f16)src[m];
        Wak[id2] = v;
    }
}

// ---------------- Phase 1: sequential carried-hidden chain. 1 WG / batch.
// 1024 threads: j = tid>>2 (row), c = tid&3 (64-wide k-chunk). Weights = 96 VGPRs.
// waves_per_eu(4,4): 16 waves = 4/EU -> 128-VGPR cap, 1 WG/CU (compiler default
// of 2 blocks/CU capped VGPRs at 64 and spilled the weights -> rounds 2-4 bug).
__global__ __attribute__((amdgpu_waves_per_eu(4, 4))) __launch_bounds__(1024)
void k_chain(
    const float* __restrict__ Whh, const float* __restrict__ bhh,
    const float* __restrict__ xw, float* __restrict__ Hc) {
    const int b = blockIdx.x;
    const int tid = threadIdx.x;
    const int j = tid >> 2, c = tid & 3;
    // chunk stride 72 halves (144 B): bank offset 4c per chunk -> conflict-free
    __shared__ __align__(16) f16 hb[2][4 * 72];

    f16x2 wr[32], wz[32], wn[32];
    {
        const float2* pr = (const float2*)(Whh + (size_t)(0 * NH + j) * NH + c * 64);
        const float2* pz = (const float2*)(Whh + (size_t)(1 * NH + j) * NH + c * 64);
        const float2* pn = (const float2*)(Whh + (size_t)(2 * NH + j) * NH + c * 64);
#pragma unroll
        for (int m = 0; m < 32; ++m) {
            float2 a = pr[m]; wr[m] = f16x2{(f16)a.x, (f16)a.y};
            float2 d = pz[m]; wz[m] = f16x2{(f16)d.x, (f16)d.y};
            float2 e = pn[m]; wn[m] = f16x2{(f16)e.x, (f16)e.y};
        }
    }
    const float bhr = bhh[j], bhz = bhh[NH + j], bhn = bhh[2 * NH + j];
    if (tid < NH) hb[0][(tid >> 6) * 72 + (tid & 63)] = (f16)0.f;
    float hprev = 0.f;
    int cur = 0;
    __syncthreads();

#pragma unroll 1
    for (int i = 0; i < NT; ++i) {
#pragma unroll 1
        for (int t = 0; t <= i; ++t) {
            const float* __restrict__ xwp = xw + (size_t)(t * NB + b) * (3 * NH);
            const float xr = xwp[j], xz = xwp[NH + j], xn = xwp[2 * NH + j];
            const f16* hc = hb[cur] + c * 72;
            float ar = 0.f, az = 0.f, an = 0.f;
#pragma unroll
            for (int s = 0; s < 8; ++s) {
                const f16x8 hv = *(const f16x8*)(hc + s * 8);
                const f16x2 h0 = PAIR(hv, 0), h1 = PAIR(hv, 2),
                            h2 = PAIR(hv, 4), h3 = PAIR(hv, 6);
                ar = fdot2_(wr[s * 4 + 0], h0, ar);
                ar = fdot2_(wr[s * 4 + 1], h1, ar);
                ar = fdot2_(wr[s * 4 + 2], h2, ar);
                ar = fdot2_(wr[s * 4 + 3], h3, ar);
                az = fdot2_(wz[s * 4 + 0], h0, az);
                az = fdot2_(wz[s * 4 + 1], h1, az);
                az = fdot2_(wz[s * 4 + 2], h2, az);
                az = fdot2_(wz[s * 4 + 3], h3, az);
                an = fdot2_(wn[s * 4 + 0], h0, an);
                an = fdot2_(wn[s * 4 + 1], h1, an);
                an = fdot2_(wn[s * 4 + 2], h2, an);
                an = fdot2_(wn[s * 4 + 3], h3, an);
            }
            ar += __shfl_xor(ar, 1); ar += __shfl_xor(ar, 2);
            az += __shfl_xor(az, 1); az += __shfl_xor(az, 2);
            an += __shfl_xor(an, 1); an += __shfl_xor(an, 2);
            const float r = sigmoidf_(xr + ar + bhr);
            const float z = sigmoidf_(xz + az + bhz);
            const float n = tanhf_(xn + r * (an + bhn));
            const float hnew = (1.f - z) * n + z * hprev;
            hprev = hnew;
            if (c == 0) {
                hb[cur ^ 1][(j >> 6) * 72 + (j & 63)] = (f16)hnew;
                if (t == i) Hc[((size_t)i * NB + b) * NH + j] = hnew;
            }
            cur ^= 1;
            __syncthreads();
        }
    }
}

// ---------------- Phase 2: lockstep re-run of all prefix chains + fused attention.
// Grid: 32 b x 8 bk; each WG owns 16 chains i = bk + 8u, 512 threads:
// col = tid>>1 (0..255), c = tid&1 (128-wide k-half). 8 waves = 2 waves/SIMD.
__global__ __attribute__((amdgpu_waves_per_eu(2, 2))) __launch_bounds__(512)
void k_attn(
    const float* __restrict__ Hc, const float* __restrict__ xw,
    const float* __restrict__ uax, const float* __restrict__ xp,
    const f16x8* __restrict__ Wpk, const f16x8* __restrict__ Wak,
    const float* __restrict__ bhh, const float* __restrict__ ba,
    const float* __restrict__ va_w, const float* __restrict__ Wo,
    const float* __restrict__ bo, float* __restrict__ out) {
    const int b  = blockIdx.x >> 3;
    const int bk = blockIdx.x & 7;
    const int tid = threadIdx.x;
    const int col = tid >> 1, c = tid & 1;
    const int lane = tid & 63, wid = tid >> 6;

    __shared__ __align__(16) float S[16][NH];
    __shared__ __align__(16) f16 Sh[16][NH];
    __shared__ float red1[8][16];
    __shared__ float mL[16], lL[16], aL[16], eL[16];
    __shared__ float redH[8][256];

    const float bhr = bhh[col], bhz = bhh[NH + col], bhn = bhh[2 * NH + col];
    const float ba_j = ba[col], va_j = va_w[col];
    float ctx[16];
#pragma unroll
    for (int u = 0; u < 16; ++u) {
        const int ic = bk + 8 * u;
        const float hv = (ic == 0) ? 0.f : Hc[((size_t)(ic - 1) * NB + b) * NH + col];
        if (c == 0) { S[u][col] = hv; Sh[u][col] = (f16)hv; }
        ctx[u] = 0.f;
    }
    if (tid < 16) { mL[tid] = -1e30f; lL[tid] = 0.f; }
    __syncthreads();

    const int imax = bk + 8 * 15;
#pragma unroll 1
    for (int t = 0; t <= imax; ++t) {
        const size_t base = (size_t)(t * NB + b);
        const float xr = xw[base * 3 * NH + col];
        const float xz = xw[base * 3 * NH + NH + col];
        const float xn = xw[base * 3 * NH + 2 * NH + col];
        const float ux = uax[base * NH + col];
        const float xpt = xp[base * NH + col];

        // ---- GRU matvec for active chains (i >= t); k-half per c
        float ar[16], az[16], an[16];
#pragma unroll
        for (int u = 0; u < 16; ++u) { ar[u] = 0.f; az[u] = 0.f; an[u] = 0.f; }
#pragma unroll 2
        for (int kk = 0; kk < 16; ++kk) {
            const int kc = kk * 2 + c;
            const f16x8 wR = Wpk[kc * 768 + col];
            const f16x8 wZ = Wpk[kc * 768 + 256 + col];
            const f16x8 wN = Wpk[kc * 768 + 512 + col];
#pragma unroll
            for (int u = 0; u < 16; ++u) {
                if (bk + 8 * u < t) continue;      // frozen chain (uniform branch)
                const f16x8 hv = *(const f16x8*)&Sh[u][kc * 8];
                const f16x2 h0 = PAIR(hv, 0), h1 = PAIR(hv, 2),
                            h2 = PAIR(hv, 4), h3 = PAIR(hv, 6);
                ar[u] = fdot2_(PAIR(wR, 0), h0, ar[u]);
                ar[u] = fdot2_(PAIR(wR, 2), h1, ar[u]);
                ar[u] = fdot2_(PAIR(wR, 4), h2, ar[u]);
                ar[u] = fdot2_(PAIR(wR, 6), h3, ar[u]);
                az[u] = fdot2_(PAIR(wZ, 0), h0, az[u]);
                az[u] = fdot2_(PAIR(wZ, 2), h1, az[u]);
                az[u] = fdot2_(PAIR(wZ, 4), h2, az[u]);
                az[u] = fdot2_(PAIR(wZ, 6), h3, az[u]);
                an[u] = fdot2_(PAIR(wN, 0), h0, an[u]);
                an[u] = fdot2_(PAIR(wN, 2), h1, an[u]);
                an[u] = fdot2_(PAIR(wN, 4), h2, an[u]);
                an[u] = fdot2_(PAIR(wN, 6), h3, an[u]);
            }
        }
        float hn[16];
#pragma unroll
        for (int u = 0; u < 16; ++u) {
            if (bk + 8 * u < t) continue;
            float arf = ar[u] + __shfl_xor(ar[u], 1);
            float azf = az[u] + __shfl_xor(az[u], 1);
            float anf = an[u] + __shfl_xor(an[u], 1);
            const float r = sigmoidf_(xr + arf + bhr);
            const float z = sigmoidf_(xz + azf + bhz);
            const float n = tanhf_(xn + r * (anf + bhn));
            hn[u] = (1.f - z) * n + z * S[u][col];
        }
        __syncthreads();                      // all Sh reads of this step done
#pragma unroll
        for (int u = 0; u < 16; ++u) {
            if (bk + 8 * u < t) continue;
            if (c == 0) { S[u][col] = hn[u]; Sh[u][col] = (f16)hn[u]; }
        }
        __syncthreads();                      // Sh now holds outs[t]

        // ---- attention scores for active chains
        float sc[16];
#pragma unroll
        for (int u = 0; u < 16; ++u) sc[u] = 0.f;
#pragma unroll 2
        for (int kk = 0; kk < 16; ++kk) {
            const int kc = kk * 2 + c;
            const f16x8 wA = Wak[kc * 256 + col];
#pragma unroll
            for (int u = 0; u < 16; ++u) {
                if (bk + 8 * u < t) continue;
                const f16x8 hv = *(const f16x8*)&Sh[u][kc * 8];
                sc[u] = fdot2_(PAIR(wA, 0), PAIR(hv, 0), sc[u]);
                sc[u] = fdot2_(PAIR(wA, 2), PAIR(hv, 2), sc[u]);
                sc[u] = fdot2_(PAIR(wA, 4), PAIR(hv, 4), sc[u]);
                sc[u] = fdot2_(PAIR(wA, 6), PAIR(hv, 6), sc[u]);
            }
        }
#pragma unroll
        for (int u = 0; u < 16; ++u) {
            if (bk + 8 * u < t) continue;
            const float sv = sc[u] + __shfl_xor(sc[u], 1);   // full-k (Wa h)[col]
            float p = (c == 0) ? va_j * tanhf_(sv + ba_j + ux) : 0.f;
#pragma unroll
            for (int off = 32; off; off >>= 1) p += __shfl_xor(p, off);
            if (lane == 0) red1[wid][u] = p;
        }
        __syncthreads();
        if (tid < 16 && bk + 8 * tid >= t) {   // online softmax state per chain
            float s = 0.f;
#pragma unroll
            for (int w = 0; w < 8; ++w) s += red1[w][tid];
            const float mo = mL[tid];
            const float mn = fmaxf(mo, s);
            const float e  = __expf(s - mn);
            const float al = __expf(mo - mn);
            lL[tid] = lL[tid] * al + e;
            mL[tid] = mn; aL[tid] = al; eL[tid] = e;
        }
        __syncthreads();
#pragma unroll
        for (int u = 0; u < 16; ++u) {
            if (bk + 8 * u < t) continue;
            ctx[u] = ctx[u] * aL[u] + eL[u] * xpt;
        }
    }

    // ---- output head per chain: logits = [h_last, context] @ Wo^T + bo
#pragma unroll 1
    for (int u = 0; u < 16; ++u) {
        const float hl = S[u][col];           // final state == h_last(i)
        const float cx = ctx[u] / lL[u];
#pragma unroll
        for (int cls = 0; cls < NC; ++cls) {
            float p = Wo[cls * (2 * NH) + col] * hl + Wo[cls * (2 * NH) + NH + col] * cx;
            p = (c == 0) ? p : 0.f;
#pragma unroll
            for (int off = 32; off; off >>= 1) p += __shfl_xor(p, off);
            if (lane == 0) redH[wid][u * 16 + cls] = p;
        }
    }
    __syncthreads();
    if (tid < 256) {
        const int u = tid >> 4, cls = tid & 15;
        const int ic = bk + 8 * u;
        float lg = bo[cls];
#pragma unroll
        for (int w = 0; w < 8; ++w) lg += redH[w][tid];
        out[((size_t)b * NT + ic) * NC + cls] = sigmoidf_(lg);
    }
}

extern "C" void kernel_launch(void* const* d_in, const int* in_sizes, int n_in,
                              void* d_out, int out_size, void* d_ws, size_t ws_size,
                              hipStream_t stream) {
    (void)in_sizes; (void)n_in; (void)out_size; (void)ws_size;
    const float* x    = (const float*)d_in[0];
    const float* W_in = (const float*)d_in[1];
    const float* b_in = (const float*)d_in[2];
    const float* Wih  = (const float*)d_in[3];
    const float* bih  = (const float*)d_in[4];
    const float* Whh  = (const float*)d_in[5];
    const float* bhh  = (const float*)d_in[6];
    const float* Wa   = (const float*)d_in[7];
    const float* ba   = (const float*)d_in[8];
    const float* Ua   = (const float*)d_in[9];
    const float* ub   = (const float*)d_in[10];
    const float* va_w = (const float*)d_in[11];
    // d_in[12] = va_b: cancels in softmax
    const float* Wo   = (const float*)d_in[13];
    const float* bo   = (const float*)d_in[14];
    float* out = (float*)d_out;

    float* ws  = (float*)d_ws;
    float* xp  = ws;                                    // NT*NB*NH        (4 MB)
    float* xw  = xp  + (size_t)NT * NB * NH;            // NT*NB*3NH       (12.6 MB)
    float* uax = xw  + (size_t)NT * NB * 3 * NH;        // NT*NB*NH        (4 MB)
    float* Hc  = uax + (size_t)NT * NB * NH;            // NT*NB*NH        (4 MB)
    f16x8* Wpk = (f16x8*)(Hc + (size_t)NT * NB * NH);   // 32*768 f16x8    (384 KB)
    f16x8* Wak = Wpk + 32 * 768;                        // 32*256 f16x8    (128 KB)

    hipLaunchKernelGGL(k_lin_in, dim3(NT * NB), dim3(256), 0, stream, x, W_in, b_in, xp);
    hipLaunchKernelGGL(k_proj,   dim3(NT * NB), dim3(256), 0, stream, xp, Wih, bih, Ua, ub, xw, uax);
    hipLaunchKernelGGL(k_pack,   dim3(128),     dim3(256), 0, stream, Whh, Wa, Wpk, Wak);
    hipLaunchKernelGGL(k_chain,  dim3(NB),      dim3(1024), 0, stream, Whh, bhh, xw, Hc);
    hipLaunchKernelGGL(k_attn,   dim3(NB * 8),  dim3(512), 0, stream,
                       Hc, xw, uax, xp, Wpk, Wak, bhh, ba, va_w, Wo, bo, out);
}